// Round 8
// baseline (110.454 us; speedup 1.0000x reference)
//
#include <hip/hip_runtime.h>

// DR splitting solver. BATCH=4096, N=96 (64 x + 32 s), M=48 (16 eq + 32 ineq).
// JF and Hessian are batch-independent => prox_g1 is an affine map y = P x + Bmat p.
//   S=(I+Q)^{-1}; T=S Jx^T; K2=Jx T+diag(0,I32); R2=K2^{-1}[T^T|E];
//   P=diag(S,I)-[T;E^T]R2; Bmat=[-P[:,:64] | R2^T]
// Iterate 10x: y=Px+c; x += clamp(2y-x,l,u)-y; out=y[:64].
//
// Round-7 lesson: compiler chose a 32-VGPR budget for the 1024-thread prep ->
// gj2x2 (~45 live floats) spilled to scratch on the serial GJ path (WRITE_SIZE
// 78->142KB). Round-8 = round-7 + amdgpu_waves_per_eu pins on both kernels to
// force sane register budgets (prep: 4 waves/EU -> 128 VGPR cap; iter: 2-3
// waves/EU -> pA[24] stays in registers).

__device__ __forceinline__ float dot4f(float4 a, float4 b) {
  return a.x*b.x + a.y*b.y + a.z*b.z + a.w*b.w;
}
__device__ __forceinline__ void ld4(const float* p, float* d) {
  float4 v = *(const float4*)p;
  d[0] = v.x; d[1] = v.y; d[2] = v.z; d[3] = v.w;
}
__device__ __forceinline__ void st4(float* p, const float* s) {
  *(float4*)p = make_float4(s[0], s[1], s[2], s[3]);
}
__device__ __forceinline__ float fastrcp(float x) {
  float r = __builtin_amdgcn_rcpf(x);
  return r * (2.0f - x * r);     // 1 Newton step: ~1e-7 rel
}
// in-place 4x4 inverse by GJ, no pivoting (SPD principal blocks)
__device__ __forceinline__ void inv4(float D[4][4]) {
  #pragma unroll
  for (int p = 0; p < 4; ++p) {
    float pi = fastrcp(D[p][p]);
    D[p][p] = pi;
    #pragma unroll
    for (int q = 0; q < 4; ++q) if (q != p) D[p][q] *= pi;
    #pragma unroll
    for (int i = 0; i < 4; ++i) if (i != p) {
      float f = D[i][p];
      #pragma unroll
      for (int q = 0; q < 4; ++q) if (q != p) D[i][q] -= f * D[p][q];
      D[i][p] = -f * pi;
    }
  }
}

// one double-buffered block-GJ step on an n x n matrix, 2x2 tile per thread.
// thread (ig2, jg2) owns rows {2ig2, 2ig2+1} x cols {2jg2, 2jg2+1}.
__device__ __forceinline__ void gj2x2(const float* __restrict__ src,
                                      float* __restrict__ dst,
                                      int b, int ig2, int jg2, int stride) {
  float D[4][4];
  #pragma unroll
  for (int r = 0; r < 4; ++r) ld4(&src[(4*b + r)*stride + 4*b], D[r]);
  float C[2][4];
  ld4(&src[(2*ig2 + 0)*stride + 4*b], C[0]);
  ld4(&src[(2*ig2 + 1)*stride + 4*b], C[1]);
  float R[4][2];
  #pragma unroll
  for (int r = 0; r < 4; ++r) {
    float2 v = *(const float2*)&src[(4*b + r)*stride + 2*jg2];
    R[r][0] = v.x; R[r][1] = v.y;
  }
  float T2[2][2];
  #pragma unroll
  for (int r = 0; r < 2; ++r) {
    float2 v = *(const float2*)&src[(2*ig2 + r)*stride + 2*jg2];
    T2[r][0] = v.x; T2[r][1] = v.y;
  }
  inv4(D);
  const bool br = (ig2 >> 1) == b, bc = (jg2 >> 1) == b;
  const int ri = (ig2 & 1) * 2, ci = (jg2 & 1) * 2;
  float W[2][2];
  if (br) {
    if (bc) {
      W[0][0] = D[ri][ci];   W[0][1] = D[ri][ci+1];
      W[1][0] = D[ri+1][ci]; W[1][1] = D[ri+1][ci+1];
    } else {
      #pragma unroll
      for (int r = 0; r < 2; ++r)
        #pragma unroll
        for (int q = 0; q < 2; ++q) {
          float s = D[ri+r][0] * R[0][q];
          #pragma unroll
          for (int k = 1; k < 4; ++k) s += D[ri+r][k] * R[k][q];
          W[r][q] = s;
        }
    }
  } else {
    float E[2][4];
    #pragma unroll
    for (int r = 0; r < 2; ++r)
      #pragma unroll
      for (int k = 0; k < 4; ++k) {
        float s = C[r][0] * D[0][k];
        #pragma unroll
        for (int m = 1; m < 4; ++m) s += C[r][m] * D[m][k];
        E[r][k] = s;
      }
    if (bc) {
      W[0][0] = -E[0][ci]; W[0][1] = -E[0][ci+1];
      W[1][0] = -E[1][ci]; W[1][1] = -E[1][ci+1];
    } else {
      #pragma unroll
      for (int r = 0; r < 2; ++r)
        #pragma unroll
        for (int q = 0; q < 2; ++q) {
          float s = T2[r][q];
          #pragma unroll
          for (int k = 0; k < 4; ++k) s -= E[r][k] * R[k][q];
          W[r][q] = s;
        }
    }
  }
  *(float2*)&dst[(2*ig2 + 0)*stride + 2*jg2] = make_float2(W[0][0], W[0][1]);
  *(float2*)&dst[(2*ig2 + 1)*stride + 2*jg2] = make_float2(W[1][0], W[1][1]);
}

// ---------------------------------------------------------------- kernel A
__global__ __launch_bounds__(1024)
__attribute__((amdgpu_waves_per_eu(4, 4)))
void prep_kernel(
    const float* __restrict__ Qg, const float* __restrict__ Ag,
    const float* __restrict__ Gg,
    float* __restrict__ Pg, float* __restrict__ Bg)
{
  // floats: 4352 + 4352 + 2496 + 4608 = 15808 = 63232 B
  __shared__ float sMa[64*68];   // M1 ping  -> S (after 16 steps)
  __shared__ float sMb[64*68];   // M1 pong  -> T (64x48, stride 48)
  __shared__ float sK [48*52];   // K2 ping  -> Ki
  __shared__ float sR2[48*96];   // Jx (s68) -> K2 pong (s52) -> R2 (s96)

#define SM_(i,j) sMa[(i)*68+(j)]
#define TT_(i,j) sMb[(i)*48+(j)]
#define SK_(i,j) sK[(i)*52+(j)]
#define JX_(a,k) sR2[(a)*68+(k)]

  const int tid = threadIdx.x;   // 0..1023

  // ---- stage Jx = [A;G] (48x64, stride 68) and M1 = Q + I
  {
    const float4* A4 = (const float4*)Ag;          // 256 quads
    const float4* G4 = (const float4*)Gg;          // 512 quads
    const float4* Q4 = (const float4*)Qg;          // 1024 quads
    if (tid < 256) {
      int a = tid >> 4, kc = tid & 15;
      st4(&JX_(a, kc*4), (const float*)&A4[tid]);
    }
    if (tid < 512) {
      int a = tid >> 4, kc = tid & 15;
      st4(&JX_(16 + a, kc*4), (const float*)&G4[tid]);
    }
    {
      int i = tid >> 4, kc = tid & 15;
      st4(&SM_(i, kc*4), (const float*)&Q4[tid]);
    }
  }
  __syncthreads();
  if (tid < 64) SM_(tid, tid) += 1.0f;
  __syncthreads();

  // ---- block-GJ 64 (dbuf, 1 barrier/step, 16 steps) -> S in sMa
  {
    const int ig2 = tid >> 5, jg2 = tid & 31;      // 32x32 tile grid
    #pragma unroll 1
    for (int p = 0; p < 8; ++p) {
      gj2x2(sMa, sMb, 2*p, ig2, jg2, 68);
      __syncthreads();
      gj2x2(sMb, sMa, 2*p + 1, ig2, jg2, 68);
      __syncthreads();
    }
  }

  // ---- T = S Jx^T : T[i][j] = sum_k S[i][k]*Jx[j][k]  (3 outputs/thread)
  #pragma unroll 1
  for (int t = tid; t < 64*48; t += 1024) {
    int i = t / 48, j = t - i*48;
    float acc = 0.0f;
    #pragma unroll 1
    for (int k = 0; k < 64; k += 4)
      acc += dot4f(*(const float4*)&SM_(i,k), *(const float4*)&JX_(j,k));
    TT_(i,j) = acc;
  }
  __syncthreads();

  // ---- K2 = Jx T + diag(0,I32)  (576 threads, 1 row x 4 cols)
  if (tid < 576) {
    int a = tid / 12, bq = tid - (tid / 12) * 12;
    int b0 = bq * 4;
    float acc[4] = {};
    #pragma unroll 1
    for (int k = 0; k < 64; ++k) {
      float jv = JX_(a, k);
      float4 tb = *(const float4*)&TT_(k, b0);
      acc[0] += jv*tb.x; acc[1] += jv*tb.y;
      acc[2] += jv*tb.z; acc[3] += jv*tb.w;
    }
    #pragma unroll
    for (int q = 0; q < 4; ++q) {
      int b = b0 + q;
      SK_(a, b) = acc[q] + ((a == b && a >= 16) ? 1.0f : 0.0f);
    }
  }
  __syncthreads();

  // ---- block-GJ 48 (dbuf; pong overlays dead Jx region) -> Ki in sK
  {
    float* KP = sR2;             // 48*52 = 2496 <= 4608
    const bool act = tid < 576;
    const int ig2 = tid / 24, jg2 = tid - (tid / 24) * 24;
    #pragma unroll 1
    for (int p = 0; p < 6; ++p) {
      if (act) gj2x2(sK, KP, 2*p, ig2, jg2, 52);
      __syncthreads();
      if (act) gj2x2(KP, sK, 2*p + 1, ig2, jg2, 52);
      __syncthreads();
    }
  }
  // KP / JX dead; sR2 region becomes R2 (stride 96).

  // ---- R2 cols<64: R2[k][c] = sum_m Ki[k][m]*T[c][m]  (3 outputs/thread)
  #pragma unroll 1
  for (int t = tid; t < 48*64; t += 1024) {
    int k = t >> 6, c = t & 63;
    float acc = 0.0f;
    #pragma unroll 1
    for (int m = 0; m < 48; m += 4)
      acc += dot4f(*(const float4*)&SK_(k,m), *(const float4*)&TT_(c,m));
    sR2[k*96 + c] = acc;
    Bg[c*112 + 64 + k] = acc;          // Bmat[:,64:] = R2^T
  }
  // ---- R2 cols>=64 (selection from Ki) -- 1536 tasks, grid-stride
  #pragma unroll 1
  for (int t = tid; t < 48*32; t += 1024) {
    int k = t >> 5, j = t & 31;
    float v = SK_(k, 16 + j);
    sR2[k*96 + 64 + j] = v;
    Bg[(64 + j)*112 + 64 + k] = v;
  }
  __syncthreads();

  // ---- P heavy rows (i<64): P = S_diag - T*R2  (1 row x 4 cols, 1536 tasks)
  #pragma unroll 1
  for (int t = tid; t < 1536; t += 1024) {
    int i = t / 24, jq = t - (t / 24) * 24;
    int j0 = jq * 4;
    float acc[4];
    #pragma unroll
    for (int q = 0; q < 4; ++q)
      acc[q] = (j0 < 64) ? SM_(i, j0 + q) : 0.0f;
    #pragma unroll 1
    for (int m = 0; m < 48; m += 4) {
      float tv[4], rv[4][4];
      ld4(&TT_(i, m), tv);
      ld4(&sR2[(m+0)*96 + j0], rv[0]);
      ld4(&sR2[(m+1)*96 + j0], rv[1]);
      ld4(&sR2[(m+2)*96 + j0], rv[2]);
      ld4(&sR2[(m+3)*96 + j0], rv[3]);
      #pragma unroll
      for (int q = 0; q < 4; ++q)
        #pragma unroll
        for (int s = 0; s < 4; ++s)
          acc[q] -= tv[s] * rv[s][q];
    }
    #pragma unroll
    for (int q = 0; q < 4; ++q) {
      int j = j0 + q;
      float v = acc[q];
      Pg[i*96 + j] = v;
      if (j0 < 64) Bg[i*112 + j] = -v;     // Bmat[:,:64] = -P[:,:64]
    }
  }
  // ---- P rows >= 64: P[64+a][j] = (64+a==j) - R2[16+a][j]
  #pragma unroll 1
  for (int t = tid; t < 32*96; t += 1024) {
    int a = t / 96, j = t - (t / 96) * 96;
    float v = ((64 + a) == j ? 1.0f : 0.0f) - sR2[(16 + a)*96 + j];
    Pg[(64 + a)*96 + j] = v;
    if (j < 64) Bg[(64 + a)*112 + j] = -v;
  }
#undef SM_
#undef TT_
#undef SK_
#undef JX_
}

// ---------------------------------------------------------------- kernel B
#define EB 8   // elements per block; grid = 512 blocks x 384 threads

__global__ __launch_bounds__(384)
__attribute__((amdgpu_waves_per_eu(2, 3)))
void iter_kernel(
    const float* __restrict__ xg, const float* __restrict__ pg,
    const float* __restrict__ Pg, const float* __restrict__ Bg,
    float* __restrict__ outg)
{
  // 4 groups x 96 rows: thread = (g, r). Thread owns P row r in registers
  // (24 float4 = 96 VGPR) for elements {2g, 2g+1}. LDS: x (static dbuf) + parms.
  __shared__ float sX[2][EB][100];
  __shared__ float sPar[EB][112];

  const int tid = threadIdx.x;          // 0..383
  const int gbase = blockIdx.x * EB;
  const int g = tid / 96;               // 0..3
  const int r = tid - 96 * g;           // 0..95
  const int e0 = 2 * g;

  // stage x (192 quads) and parms (224 quads)
  const float4* X4 = (const float4*)xg;
  if (tid < 192) {
    int e = tid / 24, kc = tid - (tid / 24) * 24;
    *(float4*)&sX[0][e][kc*4] = X4[gbase*24 + tid];
  }
  const float4* Par4 = (const float4*)pg;
  if (tid < 224) {
    int e = tid / 28, jc = tid - (tid / 28) * 28;
    *(float4*)&sPar[e][jc*4] = Par4[gbase*28 + tid];
  }

  // my P row -> registers (issued before the barrier; lands under c-phase)
  float4 pA[24];
  const float4* P4 = (const float4*)Pg;
  #pragma unroll
  for (int kq = 0; kq < 24; ++kq) pA[kq] = P4[r*24 + kq];

  __syncthreads();

  // c = Bmat(row r) @ parms(elems e0, e0+1), in registers
  float c0 = 0.f, c1 = 0.f;
  {
    const float4* B4 = (const float4*)Bg;
    #pragma unroll 1
    for (int jc = 0; jc < 28; ++jc) {
      float4 bm = B4[r*28 + jc];
      c0 += dot4f(bm, *(const float4*)&sPar[e0    ][jc*4]);
      c1 += dot4f(bm, *(const float4*)&sPar[e0 + 1][jc*4]);
    }
  }

  const float lo = (r < 64) ? -1000.0f : 0.0f;

  auto do_iter = [&](const float (*src)[100], float (*dst)[100], bool last) {
    // split accumulators: two independent 48-deep FMA chains per output
    float a0 = c0, a1 = c1, b0 = 0.f, b1 = 0.f;
    #pragma unroll
    for (int kq = 0; kq < 24; kq += 2) {
      float4 x0a = *(const float4*)&src[e0    ][kq*4];
      float4 x1a = *(const float4*)&src[e0 + 1][kq*4];
      float4 x0b = *(const float4*)&src[e0    ][kq*4 + 4];
      float4 x1b = *(const float4*)&src[e0 + 1][kq*4 + 4];
      a0 += dot4f(pA[kq],     x0a);  a1 += dot4f(pA[kq],     x1a);
      b0 += dot4f(pA[kq + 1], x0b);  b1 += dot4f(pA[kq + 1], x1b);
    }
    float y0 = a0 + b0, y1 = a1 + b1;
    if (!last) {
      float xo0 = src[e0    ][r];
      float xo1 = src[e0 + 1][r];
      float z0 = fminf(fmaxf(2.f*y0 - xo0, lo), 1000.f);
      float z1 = fminf(fmaxf(2.f*y1 - xo1, lo), 1000.f);
      dst[e0    ][r] = xo0 + z0 - y0;
      dst[e0 + 1][r] = xo1 + z1 - y1;
      __syncthreads();
    } else {
      if (r < 64) {
        outg[(gbase + e0    )*64 + r] = y0;
        outg[(gbase + e0 + 1)*64 + r] = y1;
      }
    }
  };

  do_iter(sX[0], sX[1], false);   // it 0
  do_iter(sX[1], sX[0], false);   // it 1
  do_iter(sX[0], sX[1], false);   // it 2
  do_iter(sX[1], sX[0], false);   // it 3
  do_iter(sX[0], sX[1], false);   // it 4
  do_iter(sX[1], sX[0], false);   // it 5
  do_iter(sX[0], sX[1], false);   // it 6
  do_iter(sX[1], sX[0], false);   // it 7
  do_iter(sX[0], sX[1], false);   // it 8
  do_iter(sX[1], sX[0], true);    // it 9 -> output
}

// ---------------------------------------------------------------- launch
extern "C" void kernel_launch(void* const* d_in, const int* in_sizes, int n_in,
                              void* d_out, int out_size, void* d_ws, size_t ws_size,
                              hipStream_t stream) {
  const float* x     = (const float*)d_in[0];   // (4096, 96)
  const float* parms = (const float*)d_in[1];   // (4096, 112)
  const float* Qg    = (const float*)d_in[2];   // (64, 64)
  const float* Ag    = (const float*)d_in[3];   // (16, 64)
  const float* Gg    = (const float*)d_in[4];   // (32, 64)
  float* out = (float*)d_out;                   // (4096, 64)

  float* ws  = (float*)d_ws;
  float* Pg  = ws;               // 96*96  = 9216
  float* Bg  = ws + 9216;        // 96*112 = 10752

  prep_kernel<<<1, 1024, 0, stream>>>(Qg, Ag, Gg, Pg, Bg);
  iter_kernel<<<4096 / EB, 384, 0, stream>>>(x, parms, Pg, Bg, out);
}

// Round 9
// 78.483 us; speedup vs baseline: 1.4074x; 1.4074x over previous
//
#include <hip/hip_runtime.h>

// DR splitting solver. BATCH=4096, N=96 (64 x + 32 s), M=48 (16 eq + 32 ineq).
// JF and Hessian are batch-independent => prox_g1 is an affine map y = P x + Bmat p.
//   S=(I+Q)^{-1}; T=S Jx^T; K2=Jx T+diag(0,I32); R2=K2^{-1}[T^T|E];
//   P=diag(S,I)-[T;E^T]R2; Bmat=[-P[:,:64] | R2^T]
// Iterate 10x: y=Px+c; x += clamp(2y-x,l,u)-y; out=y[:64].
//
// Round-8 lessons: (a) waves_per_eu didn't stop spilling at 1024 thr -> revert
// prep to the proven 256-thr shape (r5: VGPR 88, no spill); (b) iter is LDS-
// instruction-issue bound (48 b128 broadcasts/thread/iter); instructions scale
// 1/R -> R=2 rows/thread (192 VGPR of P) halves them; (c) prep's unroll-1 inner
// dots serialized LDS latency -> unroll 4 + 4x3-tiled T phase.

__device__ __forceinline__ float dot4f(float4 a, float4 b) {
  return a.x*b.x + a.y*b.y + a.z*b.z + a.w*b.w;
}
__device__ __forceinline__ void ld4(const float* p, float* d) {
  float4 v = *(const float4*)p;
  d[0] = v.x; d[1] = v.y; d[2] = v.z; d[3] = v.w;
}
__device__ __forceinline__ void st4(float* p, const float* s) {
  *(float4*)p = make_float4(s[0], s[1], s[2], s[3]);
}
__device__ __forceinline__ float fastrcp(float x) {
  float r = __builtin_amdgcn_rcpf(x);
  return r * (2.0f - x * r);     // 1 Newton step: ~1e-7 rel
}
// W = A*B (4x4)
__device__ __forceinline__ void mm4(float W[4][4], const float A[4][4], const float B[4][4]) {
  #pragma unroll
  for (int r = 0; r < 4; ++r)
    #pragma unroll
    for (int q = 0; q < 4; ++q) {
      float s = A[r][0]*B[0][q];
      #pragma unroll
      for (int k = 1; k < 4; ++k) s += A[r][k]*B[k][q];
      W[r][q] = s;
    }
}
// in-place 4x4 inverse by GJ, no pivoting (SPD principal blocks)
__device__ __forceinline__ void inv4(float D[4][4]) {
  #pragma unroll
  for (int p = 0; p < 4; ++p) {
    float pi = fastrcp(D[p][p]);
    D[p][p] = pi;
    #pragma unroll
    for (int q = 0; q < 4; ++q) if (q != p) D[p][q] *= pi;
    #pragma unroll
    for (int i = 0; i < 4; ++i) if (i != p) {
      float f = D[i][p];
      #pragma unroll
      for (int q = 0; q < 4; ++q) if (q != p) D[i][q] -= f * D[p][q];
      D[i][p] = -f * pi;
    }
  }
}

// one double-buffered block-GJ step, stride 68 (64x64), all 256 threads
__device__ __forceinline__ void gj_step64(const float* __restrict__ src,
                                          float* __restrict__ dst,
                                          int b, int ig, int jg) {
  float D[4][4], C[4][4], R[4][4], T4[4][4], W[4][4];
  #pragma unroll
  for (int r = 0; r < 4; ++r) {
    ld4(&src[(4*b + r)*68 + 4*b],  D[r]);
    ld4(&src[(4*ig + r)*68 + 4*b], C[r]);
    ld4(&src[(4*b + r)*68 + 4*jg], R[r]);
    ld4(&src[(4*ig + r)*68 + 4*jg], T4[r]);
  }
  inv4(D);
  if (ig == b) {
    if (jg == b) {
      #pragma unroll
      for (int r = 0; r < 4; ++r)
        #pragma unroll
        for (int q = 0; q < 4; ++q) W[r][q] = D[r][q];
    } else {
      mm4(W, D, R);
    }
  } else {
    float E[4][4];
    mm4(E, C, D);
    if (jg == b) {
      #pragma unroll
      for (int r = 0; r < 4; ++r)
        #pragma unroll
        for (int q = 0; q < 4; ++q) W[r][q] = -E[r][q];
    } else {
      #pragma unroll
      for (int r = 0; r < 4; ++r)
        #pragma unroll
        for (int q = 0; q < 4; ++q) {
          float s = T4[r][q];
          #pragma unroll
          for (int k = 0; k < 4; ++k) s -= E[r][k] * R[k][q];
          W[r][q] = s;
        }
    }
  }
  #pragma unroll
  for (int r = 0; r < 4; ++r) st4(&dst[(4*ig + r)*68 + 4*jg], W[r]);
  __syncthreads();
}

// one double-buffered block-GJ step, stride 52 (48x48), threads 0..143 active
__device__ __forceinline__ void gj_step48(const float* __restrict__ src,
                                          float* __restrict__ dst,
                                          int b, int tid) {
  const bool act = tid < 144;
  const int ig = tid / 12, jg = tid - (tid / 12) * 12;
  float D[4][4], C[4][4], R[4][4], T4[4][4], W[4][4];
  if (act) {
    #pragma unroll
    for (int r = 0; r < 4; ++r) {
      ld4(&src[(4*b + r)*52 + 4*b],  D[r]);
      ld4(&src[(4*ig + r)*52 + 4*b], C[r]);
      ld4(&src[(4*b + r)*52 + 4*jg], R[r]);
      ld4(&src[(4*ig + r)*52 + 4*jg], T4[r]);
    }
    inv4(D);
    if (ig == b) {
      if (jg == b) {
        #pragma unroll
        for (int r = 0; r < 4; ++r)
          #pragma unroll
          for (int q = 0; q < 4; ++q) W[r][q] = D[r][q];
      } else {
        mm4(W, D, R);
      }
    } else {
      float E[4][4];
      mm4(E, C, D);
      if (jg == b) {
        #pragma unroll
        for (int r = 0; r < 4; ++r)
          #pragma unroll
          for (int q = 0; q < 4; ++q) W[r][q] = -E[r][q];
      } else {
        #pragma unroll
        for (int r = 0; r < 4; ++r)
          #pragma unroll
          for (int q = 0; q < 4; ++q) {
            float s = T4[r][q];
            #pragma unroll
            for (int k = 0; k < 4; ++k) s -= E[r][k] * R[k][q];
            W[r][q] = s;
          }
      }
    }
    #pragma unroll
    for (int r = 0; r < 4; ++r) st4(&dst[(4*ig + r)*52 + 4*jg], W[r]);
  }
  __syncthreads();
}

// ---------------------------------------------------------------- kernel A
__global__ __launch_bounds__(256, 1) void prep_kernel(
    const float* __restrict__ Qg, const float* __restrict__ Ag,
    const float* __restrict__ Gg,
    float* __restrict__ Pg, float* __restrict__ Bg)
{
  // floats: 4352 + 4352 + 2496 + 4608 = 15808 = 63232 B
  __shared__ float sMa[64*68];   // M1 ping  -> S (after 16 steps)
  __shared__ float sMb[64*68];   // M1 pong  -> T (64x48, stride 48)
  __shared__ float sK [48*52];   // K2 ping  -> Ki
  __shared__ float sR2[48*96];   // Jx (s68) -> K2 pong (s52) -> R2 (s96)

#define SM_(i,j) sMa[(i)*68+(j)]
#define TT_(i,j) sMb[(i)*48+(j)]
#define SK_(i,j) sK[(i)*52+(j)]
#define JX_(a,k) sR2[(a)*68+(k)]

  const int tid = threadIdx.x;
  const int ig = tid >> 4, jg = tid & 15;

  // ---- stage Jx = [A;G] (48x64, stride 68) and M1 = Q + I
  {
    const float4* A4 = (const float4*)Ag;          // 256 quads
    const float4* G4 = (const float4*)Gg;          // 512 quads
    {
      int t = tid;
      int a = t >> 4, kc = t & 15;
      st4(&JX_(a, kc*4), (const float*)&A4[t]);
    }
    for (int t = tid; t < 512; t += 256) {
      int a = t >> 4, kc = t & 15;
      st4(&JX_(16 + a, kc*4), (const float*)&G4[t]);
    }
    const float4* Q4 = (const float4*)Qg;          // 1024 quads
    for (int t = tid; t < 1024; t += 256) {
      int i = t >> 4, kc = t & 15;
      st4(&SM_(i, kc*4), (const float*)&Q4[t]);
    }
  }
  __syncthreads();
  if (tid < 64) SM_(tid, tid) += 1.0f;
  __syncthreads();

  // ---- block-GJ 64 (dbuf, 1 barrier/step, 16 steps) -> S in sMa
  #pragma unroll 1
  for (int p = 0; p < 8; ++p) {
    gj_step64(sMa, sMb, 2*p,     ig, jg);
    gj_step64(sMb, sMa, 2*p + 1, ig, jg);
  }

  // ---- T = S Jx^T : 4x3 register tile/thread (16 ig x 16 jg covers 64x48)
  {
    const int i0 = 4*ig, j0 = 3*jg;
    float acc[4][3] = {};
    #pragma unroll 4
    for (int kq = 0; kq < 16; ++kq) {
      float sv[4][4], jv[3][4];
      ld4(&SM_(i0+0, kq*4), sv[0]); ld4(&SM_(i0+1, kq*4), sv[1]);
      ld4(&SM_(i0+2, kq*4), sv[2]); ld4(&SM_(i0+3, kq*4), sv[3]);
      ld4(&JX_(j0+0, kq*4), jv[0]); ld4(&JX_(j0+1, kq*4), jv[1]);
      ld4(&JX_(j0+2, kq*4), jv[2]);
      #pragma unroll
      for (int r = 0; r < 4; ++r)
        #pragma unroll
        for (int c = 0; c < 3; ++c)
          #pragma unroll
          for (int s = 0; s < 4; ++s)
            acc[r][c] += sv[r][s] * jv[c][s];
    }
    __syncthreads();   // SM/JX reads done (paranoia before TT writes to sMb pong)
    #pragma unroll
    for (int r = 0; r < 4; ++r)
      #pragma unroll
      for (int c = 0; c < 3; ++c)
        TT_(i0+r, j0+c) = acc[r][c];
  }
  __syncthreads();

  // ---- K2 = Jx T + diag(0,I32)  (192 threads, 3x4 tiles)
  if (tid < 192) {
    int ag = tid / 12, bg = tid - ag*12;
    int a0 = ag*3, b0 = bg*4;
    float acc[3][4] = {};
    #pragma unroll 4
    for (int k = 0; k < 64; ++k) {
      float4 tb = *(const float4*)&TT_(k,b0);
      #pragma unroll
      for (int r = 0; r < 3; ++r) {
        float jv = JX_(a0 + r, k);
        acc[r][0] += jv*tb.x; acc[r][1] += jv*tb.y;
        acc[r][2] += jv*tb.z; acc[r][3] += jv*tb.w;
      }
    }
    #pragma unroll
    for (int r = 0; r < 3; ++r)
      #pragma unroll
      for (int q = 0; q < 4; ++q) {
        int a = a0 + r, b = b0 + q;
        SK_(a,b) = acc[r][q] + ((a == b && a >= 16) ? 1.0f : 0.0f);
      }
  }
  __syncthreads();

  // ---- block-GJ 48 (dbuf; pong overlays dead Jx region) -> Ki in sK
  {
    float* KP = sR2;   // 48*52 = 2496 <= 4608
    #pragma unroll 1
    for (int p = 0; p < 6; ++p) {
      gj_step48(sK, KP, 2*p,     tid);
      gj_step48(KP, sK, 2*p + 1, tid);
    }
  }
  // KP / JX dead; sR2 region becomes R2 (stride 96).

  // ---- R2 cols<64: R2[k][c] = sum_m Ki[k][m]*T[c][m]  (3k x 4c tiles)
  {
    int kg = tid >> 4, cg = tid & 15;
    int k0 = kg*3, c0 = cg*4;
    float acc[3][4] = {};
    #pragma unroll 4
    for (int m = 0; m < 48; m += 4) {
      float kv[3][4], tv[4][4];
      ld4(&SK_(k0+0,m), kv[0]); ld4(&SK_(k0+1,m), kv[1]); ld4(&SK_(k0+2,m), kv[2]);
      ld4(&TT_(c0+0,m), tv[0]); ld4(&TT_(c0+1,m), tv[1]);
      ld4(&TT_(c0+2,m), tv[2]); ld4(&TT_(c0+3,m), tv[3]);
      #pragma unroll
      for (int r = 0; r < 3; ++r)
        #pragma unroll
        for (int q = 0; q < 4; ++q)
          #pragma unroll
          for (int s = 0; s < 4; ++s)
            acc[r][q] += kv[r][s] * tv[q][s];
    }
    #pragma unroll
    for (int r = 0; r < 3; ++r)
      #pragma unroll
      for (int q = 0; q < 4; ++q) {
        int k = k0 + r, c = c0 + q;
        float v = acc[r][q];
        sR2[k*96 + c] = v;
        Bg[c*112 + 64 + k] = v;       // Bmat[:,64:] = R2^T
      }
  }
  // R2 cols>=64 (selection from Ki)
  #pragma unroll 1
  for (int t = tid; t < 48*32; t += 256) {
    int k = t >> 5, j = t & 31;
    float v = SK_(k, 16 + j);
    sR2[k*96 + 64 + j] = v;
    Bg[(64 + j)*112 + 64 + k] = v;
  }
  __syncthreads();

  // ---- P heavy rows (i<64): P = S_diag - T*R2  (16 ig x 24 jc tasks)
  #pragma unroll 1
  for (int task = tid; task < 384; task += 256) {
    int tg = task / 24, jc = task - tg*24;
    int i0 = tg*4, j0 = jc*4;
    float acc[4][4];
    #pragma unroll
    for (int r = 0; r < 4; ++r)
      #pragma unroll
      for (int q = 0; q < 4; ++q)
        acc[r][q] = (j0 < 64) ? SM_(i0+r, j0+q) : 0.0f;
    #pragma unroll 4
    for (int m = 0; m < 48; m += 4) {
      float tv[4][4], rv[4][4];
      ld4(&TT_(i0+0,m), tv[0]); ld4(&TT_(i0+1,m), tv[1]);
      ld4(&TT_(i0+2,m), tv[2]); ld4(&TT_(i0+3,m), tv[3]);
      ld4(&sR2[(m+0)*96 + j0], rv[0]);
      ld4(&sR2[(m+1)*96 + j0], rv[1]);
      ld4(&sR2[(m+2)*96 + j0], rv[2]);
      ld4(&sR2[(m+3)*96 + j0], rv[3]);
      #pragma unroll
      for (int r = 0; r < 4; ++r)
        #pragma unroll
        for (int q = 0; q < 4; ++q)
          #pragma unroll
          for (int s = 0; s < 4; ++s)
            acc[r][q] -= tv[r][s] * rv[s][q];
    }
    #pragma unroll
    for (int r = 0; r < 4; ++r)
      #pragma unroll
      for (int q = 0; q < 4; ++q) {
        int i = i0 + r, j = j0 + q;
        float v = acc[r][q];
        Pg[i*96 + j] = v;
        if (j0 < 64) Bg[i*112 + j] = -v;   // Bmat[:,:64] = -P[:,:64]
      }
  }
  // ---- P rows >= 64: P[64+a][j] = (64+a==j) - R2[16+a][j]
  #pragma unroll 1
  for (int t = tid; t < 32*96; t += 256) {
    int a = t / 96, j = t - (t / 96) * 96;
    float v = ((64 + a) == j ? 1.0f : 0.0f) - sR2[(16 + a)*96 + j];
    Pg[(64 + a)*96 + j] = v;
    if (j < 64) Bg[(64 + a)*112 + j] = -v;
  }
#undef SM_
#undef TT_
#undef SK_
#undef JX_
}

// ---------------------------------------------------------------- kernel B
#define EB 16   // elements per block; grid = 256 blocks x 384 threads (1/CU)

__global__ __launch_bounds__(384, 1) void iter_kernel(
    const float* __restrict__ xg, const float* __restrict__ pg,
    const float* __restrict__ Pg, const float* __restrict__ Bg,
    float* __restrict__ outg)
{
  // Thread = (egroup 0..7, rgroup 0..47): owns P rows {2rg, 2rg+1} in
  // registers (48 float4 = 192 VGPR) x elements {2eg, 2eg+1}. R=2 halves
  // the per-iter LDS broadcast-read instruction count vs R=1 (the wall).
  __shared__ float sX[2][EB][100];
  __shared__ float sPar[EB][112];

  const int tid = threadIdx.x;          // 0..383
  const int gbase = blockIdx.x * EB;
  const int eg = tid / 48;              // 0..7
  const int rg = tid - 48 * eg;         // 0..47
  const int e0 = 2 * eg, r0 = 2 * rg;

  // stage x (384 quads, exactly 1/thread) and parms (448 quads)
  const float4* X4 = (const float4*)xg;
  {
    int e = tid / 24, kc = tid - 24 * (tid / 24);
    *(float4*)&sX[0][e][kc*4] = X4[gbase*24 + tid];
  }
  const float4* Par4 = (const float4*)pg;
  for (int t = tid; t < EB*28; t += 384) {
    int e = t / 28, jc = t - 28 * e;
    *(float4*)&sPar[e][jc*4] = Par4[gbase*28 + t];
  }

  // my 2 P rows -> registers (issued before barrier; lands under c-phase)
  float4 pA[24], pB[24];
  const float4* P4 = (const float4*)Pg;
  #pragma unroll
  for (int kq = 0; kq < 24; ++kq) pA[kq] = P4[r0*24 + kq];
  #pragma unroll
  for (int kq = 0; kq < 24; ++kq) pB[kq] = P4[(r0+1)*24 + kq];

  __syncthreads();

  // c = Bmat(rows r0,r0+1) @ parms(elems e0,e0+1)
  float c00 = 0.f, c01 = 0.f, c10 = 0.f, c11 = 0.f;
  {
    const float4* B4 = (const float4*)Bg;
    #pragma unroll 4
    for (int jc = 0; jc < 28; ++jc) {
      float4 b0 = B4[r0*28 + jc];
      float4 b1 = B4[(r0+1)*28 + jc];
      float4 q0 = *(const float4*)&sPar[e0    ][jc*4];
      float4 q1 = *(const float4*)&sPar[e0 + 1][jc*4];
      c00 += dot4f(b0, q0); c01 += dot4f(b0, q1);
      c10 += dot4f(b1, q0); c11 += dot4f(b1, q1);
    }
  }

  const float lo = (r0 < 64) ? -1000.0f : 0.0f;
  const float* curb = &sX[0][0][0];
  float* nxtb = &sX[1][0][0];

  #pragma unroll 1
  for (int it = 0; it < 10; ++it) {
    float a00 = c00, a01 = c01, a10 = c10, a11 = c11;
    const float* x0p = curb + e0 * 100;
    const float* x1p = curb + (e0 + 1) * 100;
    #pragma unroll
    for (int kq = 0; kq < 24; ++kq) {
      float4 x0 = *(const float4*)(x0p + kq*4);
      float4 x1 = *(const float4*)(x1p + kq*4);
      a00 += dot4f(pA[kq], x0); a01 += dot4f(pA[kq], x1);
      a10 += dot4f(pB[kq], x0); a11 += dot4f(pB[kq], x1);
    }
    if (it < 9) {
      float2 xo0 = *(const float2*)(x0p + r0);
      float2 xo1 = *(const float2*)(x1p + r0);
      float z00 = fminf(fmaxf(2.f*a00 - xo0.x, lo), 1000.f);
      float z10 = fminf(fmaxf(2.f*a10 - xo0.y, lo), 1000.f);
      float z01 = fminf(fmaxf(2.f*a01 - xo1.x, lo), 1000.f);
      float z11 = fminf(fmaxf(2.f*a11 - xo1.y, lo), 1000.f);
      *(float2*)(nxtb + e0*100 + r0) =
          make_float2(xo0.x + z00 - a00, xo0.y + z10 - a10);
      *(float2*)(nxtb + (e0+1)*100 + r0) =
          make_float2(xo1.x + z01 - a01, xo1.y + z11 - a11);
      __syncthreads();
      float* t = (float*)curb; curb = nxtb; nxtb = t;
    } else {
      if (r0 < 64) {
        *(float2*)&outg[(gbase + e0    )*64 + r0] = make_float2(a00, a10);
        *(float2*)&outg[(gbase + e0 + 1)*64 + r0] = make_float2(a01, a11);
      }
    }
  }
}

// ---------------------------------------------------------------- launch
extern "C" void kernel_launch(void* const* d_in, const int* in_sizes, int n_in,
                              void* d_out, int out_size, void* d_ws, size_t ws_size,
                              hipStream_t stream) {
  const float* x     = (const float*)d_in[0];   // (4096, 96)
  const float* parms = (const float*)d_in[1];   // (4096, 112)
  const float* Qg    = (const float*)d_in[2];   // (64, 64)
  const float* Ag    = (const float*)d_in[3];   // (16, 64)
  const float* Gg    = (const float*)d_in[4];   // (32, 64)
  float* out = (float*)d_out;                   // (4096, 64)

  float* ws  = (float*)d_ws;
  float* Pg  = ws;               // 96*96  = 9216
  float* Bg  = ws + 9216;        // 96*112 = 10752

  prep_kernel<<<1, 256, 0, stream>>>(Qg, Ag, Gg, Pg, Bg);
  iter_kernel<<<4096 / EB, 384, 0, stream>>>(x, parms, Pg, Bg, out);
}